// Round 1
// baseline (477.624 us; speedup 1.0000x reference)
//
#include <hip/hip_runtime.h>

// MultiHeadAttention_86079734546451 — MI355X bf16 MFMA pipeline.
// B=16 S=14 N=128 D=512 H=8 d=64 L=12, NS=N*S=1792.
// Stages: wconv -> transpose(q,k,v) -> QKV proj GEMM -> bias einsum -> attention -> out GEMM.
// Workspace (u16 elements):
//   [0 .. 44,040,192)        xT (q/k/v transposed bf16)   -- later overlaid by biasws+attn_out
//   [44,040,192 .. 88,080,384) qh/kh/vh  [b][s][h][n][d] bf16
//   [88,080,384 .. +1,048,576) weights bf16 (Wq*0.125, Wk, Wv, Wo)
// Peak ws = 178,257,920 bytes.

typedef unsigned short u16;
typedef __bf16 bf16x8 __attribute__((ext_vector_type(8)));
typedef float f32x4 __attribute__((ext_vector_type(4)));

__device__ __forceinline__ u16 f2bf(float f) {
  unsigned u = __float_as_uint(f);
  u += 0x7fffu + ((u >> 16) & 1u);   // RTNE (inputs are finite)
  return (u16)(u >> 16);
}
__device__ __forceinline__ float bf2f(u16 b) {
  return __uint_as_float(((unsigned)b) << 16);
}

// ---------------- weight convert: fp32 -> bf16, Wq scaled by 1/8 ----------------
__global__ __launch_bounds__(256) void wconv_kernel(const float* __restrict__ Wq, const float* __restrict__ Wk,
                                                    const float* __restrict__ Wv, const float* __restrict__ Wo,
                                                    u16* __restrict__ wbf) {
  int idx = (blockIdx.x * 256 + threadIdx.x) * 4;     // 1024 blocks -> 2^20 elems
  int m = idx >> 18;
  int r = idx & 262143;
  const float* src = (m == 0) ? Wq : (m == 1) ? Wk : (m == 2) ? Wv : Wo;
  float sc = (m == 0) ? 0.125f : 1.0f;                // fold d^-0.5 into Wq
  float4 v = *(const float4*)&src[r];
  ushort4 o;
  o.x = f2bf(v.x * sc); o.y = f2bf(v.y * sc); o.z = f2bf(v.z * sc); o.w = f2bf(v.w * sc);
  *(ushort4*)&wbf[idx] = o;
}

// ---------------- transpose q/k/v: [b][D][NS] f32 -> [b][NS][D] bf16 ----------------
__global__ __launch_bounds__(256) void transpose_kernel(const float* __restrict__ q, const float* __restrict__ k,
                                                        const float* __restrict__ v, u16* __restrict__ xT) {
  __shared__ u16 tile[64 * 76];                       // [d-local][ns-local], pad 76
  const int nst = blockIdx.x;                         // 0..27
  const int dt  = blockIdx.y;                         // 0..7
  const int z   = blockIdx.z;                         // which*16 + b
  const int which = z >> 4, b = z & 15;
  const float* src = (which == 0) ? q : (which == 1) ? k : v;
  u16* dst = xT + which * 14680064;
  const int t = threadIdx.x;
  const int c4 = t & 15, r0 = t >> 4;
#pragma unroll
  for (int it = 0; it < 4; ++it) {
    int r = r0 + it * 16;                             // d-local
    float4 f = *(const float4*)&src[(b * 512 + dt * 64 + r) * 1792 + nst * 64 + c4 * 4];
    ushort4 o; o.x = f2bf(f.x); o.y = f2bf(f.y); o.z = f2bf(f.z); o.w = f2bf(f.w);
    *(ushort4*)&tile[r * 76 + c4 * 4] = o;
  }
  __syncthreads();
  const int dq = t & 15, nr0 = t >> 4;
#pragma unroll
  for (int it = 0; it < 4; ++it) {
    int nr = nr0 + it * 16;                           // ns-local
    ushort4 o;
    o.x = tile[(dq * 4 + 0) * 76 + nr];
    o.y = tile[(dq * 4 + 1) * 76 + nr];
    o.z = tile[(dq * 4 + 2) * 76 + nr];
    o.w = tile[(dq * 4 + 3) * 76 + nr];
    *(ushort4*)&dst[(b * 1792 + nst * 64 + nr) * 512 + dt * 64 + dq * 4] = o;
  }
}

// ---------------- shared 128x128x512 bf16 GEMM body (A[128][512], BT[128][512], both k-contig) ----------------
// LDS tiles laid out [kk][128][32] so ds_read_b128 hits the 8-lane/bank-quad floor.
__device__ __forceinline__ void gemm128(const u16* __restrict__ Ag, const u16* __restrict__ Bg,
                                        u16* sA, u16* sB, f32x4 acc[2][8]) {
  const int t = threadIdx.x;
  const int w = t >> 6, l = t & 63;
  const int lw = l >> 4, ll16 = l & 15;
  for (int kb = 0; kb < 8; ++kb) {                    // K = 512, BK = 64
#pragma unroll
    for (int it = 0; it < 4; ++it) {
      int i = t + 256 * it;                           // 0..1023 chunk id
      int row = i >> 3, g = i & 7;
      int so = ((g >> 2) << 12) + row * 32 + (g & 3) * 8;
      int go = row * 512 + kb * 64 + g * 8;
      *(uint4*)&sA[so] = *(const uint4*)&Ag[go];
      *(uint4*)&sB[so] = *(const uint4*)&Bg[go];
    }
    __syncthreads();
#pragma unroll
    for (int kk = 0; kk < 2; ++kk) {
      const int ko = (kk << 12) + lw * 8;
      bf16x8 a0 = *(const bf16x8*)&sA[ko + (w * 32 + ll16) * 32];
      bf16x8 a1 = *(const bf16x8*)&sA[ko + (w * 32 + 16 + ll16) * 32];
#pragma unroll
      for (int mt = 0; mt < 8; ++mt) {
        bf16x8 bb = *(const bf16x8*)&sB[ko + (mt * 16 + ll16) * 32];
        acc[0][mt] = __builtin_amdgcn_mfma_f32_16x16x32_bf16(a0, bb, acc[0][mt], 0, 0, 0);
        acc[1][mt] = __builtin_amdgcn_mfma_f32_16x16x32_bf16(a1, bb, acc[1][mt], 0, 0, 0);
      }
    }
    __syncthreads();
  }
}

// ---------------- QKV projection: C[ns][e] = xT[ns][:] @ W[e][:]^T + b ----------------
// scatter epilogue -> qh/kh/vh [b][s][h][n][d] bf16
__global__ __launch_bounds__(256) void proj_kernel(const u16* __restrict__ xT, const u16* __restrict__ wbf,
                                                   const float* __restrict__ bq, const float* __restrict__ bk,
                                                   const float* __restrict__ bv, u16* __restrict__ qh) {
  __shared__ u16 sA[8192], sB[8192];
  const int bx = blockIdx.x;                          // e-tile 0..3
  const int by = blockIdx.y;                          // ns-tile 0..13
  const int z  = blockIdx.z;                          // p*16 + b
  const int p = z >> 4, b = z & 15;
  const u16* Ag = xT + p * 14680064 + b * 917504 + by * 65536;
  const u16* Bg = wbf + p * 262144 + bx * 65536;
  const float* bvec = (p == 0) ? bq : (p == 1) ? bk : bv;
  const float bscale = (p == 0) ? 0.125f : 1.0f;
  u16* outp = qh + p * 14680064;

  f32x4 acc[2][8];
#pragma unroll
  for (int i = 0; i < 2; ++i)
#pragma unroll
    for (int j = 0; j < 8; ++j)
#pragma unroll
      for (int e = 0; e < 4; ++e) acc[i][j][e] = 0.f;

  gemm128(Ag, Bg, sA, sB, acc);

  const int t = threadIdx.x, w = t >> 6, l = t & 63;
  const int lw = l >> 4, ll16 = l & 15;
#pragma unroll
  for (int mt = 0; mt < 8; ++mt) {
    int e = bx * 128 + mt * 16 + ll16;
    float bias = bvec[e] * bscale;
    int hh = e >> 6, dd = e & 63;
#pragma unroll
    for (int nt = 0; nt < 2; ++nt) {
#pragma unroll
      for (int j = 0; j < 4; ++j) {
        unsigned row = by * 128 + w * 32 + nt * 16 + lw * 4 + j;  // ns within b, 0..1791
        unsigned n = row / 14u;
        unsigned sI = row - n * 14u;
        outp[(((b * 14 + sI) * 8 + hh) << 13) + n * 64 + dd] = f2bf(acc[nt][mt][j] + bias);
      }
    }
  }
}

// ---------------- bias: [B,L,N,N,H] @ Wd[s,l] + bd -> biasws [b][s][h][n][m] bf16 ----------------
__global__ __launch_bounds__(256) void bias_kernel(const float* __restrict__ ab, const float* __restrict__ Wd,
                                                   const float* __restrict__ bd, u16* __restrict__ biasws) {
  __shared__ float abt[12 * 520];                     // [l][h][m] : l*520 + h*65 + m
  __shared__ float sWd[168];
  __shared__ float sbd[14];
  const int m0 = blockIdx.x * 64;                     // 0 or 64
  const int n  = blockIdx.y;                          // 0..127
  const int b  = blockIdx.z;                          // 0..15
  const int t = threadIdx.x;
  if (t < 168) sWd[t] = Wd[t];
  if (t < 14)  sbd[t] = bd[t];
#pragma unroll
  for (int it = 0; it < 24; ++it) {
    int i = t + 256 * it;                             // 0..6143
    int lI = i >> 9, rem = i & 511;
    int m = rem >> 3, hI = rem & 7;
    float v = ab[((b * 12 + lI) * 16384 + n * 128 + m0 + m) * 8 + hI];
    abt[lI * 520 + hI * 65 + m] = v;
  }
  __syncthreads();
  const int m = t & 63, qq = t >> 6;
#pragma unroll
  for (int hh = 0; hh < 2; ++hh) {
    int h = qq * 2 + hh;
    float v[12];
#pragma unroll
    for (int lI = 0; lI < 12; ++lI) v[lI] = abt[lI * 520 + h * 65 + m];
#pragma unroll
    for (int sI = 0; sI < 14; ++sI) {
      float r = sbd[sI];
#pragma unroll
      for (int lI = 0; lI < 12; ++lI) r += v[lI] * sWd[sI * 12 + lI];
      biasws[((b * 14 + sI) * 8 + h) * 16384 + n * 128 + m0 + m] = f2bf(r);
    }
  }
}

// ---------------- attention: per (b,s,h); softmax over n (rows) per column m ----------------
__global__ __launch_bounds__(256) void attn_kernel(const u16* __restrict__ qh, const u16* __restrict__ kh,
                                                   const u16* __restrict__ vh, const u16* __restrict__ biasws,
                                                   u16* __restrict__ attn_out) {
  __shared__ u16 smem[24576];                         // 48 KB
  u16* sQ = smem;                                     // [2][128][32]
  u16* sK = smem + 8192;                              // [2][128][32]
  u16* sV = smem + 16384;                             // B-frag layout: (m>>3)*512 + (d>>4)*128 + (d&15)*8 + (m&7)
  u16* sP = smem;                                     // [4][128][32] overlays sQ+sK after QK^T

  const int sI = blockIdx.x, h = blockIdx.y, b = blockIdx.z;
  const int t = threadIdx.x, w = t >> 6, l = t & 63;
  const int lw = l >> 4, ll16 = l & 15;
  const int bsh = ((b * 14 + sI) * 8 + h) << 13;      // *8192

  // stage Q, K (linear rows -> [kk][128][32])
#pragma unroll
  for (int it = 0; it < 4; ++it) {
    int i = t + 256 * it;
    int row = i >> 3, g = i & 7;
    int so = ((g >> 2) << 12) + row * 32 + (g & 3) * 8;
    *(uint4*)&sQ[so] = *(const uint4*)&qh[bsh + row * 64 + g * 8];
    *(uint4*)&sK[so] = *(const uint4*)&kh[bsh + row * 64 + g * 8];
  }
  // stage V into PV B-fragment layout
#pragma unroll
  for (int it = 0; it < 4; ++it) {
    int m = (t >> 3) + 32 * it;                       // 0..127
    int dd0 = (t & 7) * 8;
    uint4 u = *(const uint4*)&vh[bsh + m * 64 + dd0];
    const u16* pu = (const u16*)&u;
    int mo = (m >> 3) * 512 + (m & 7);
#pragma unroll
    for (int j = 0; j < 8; ++j) {
      int d = dd0 + j;
      sV[mo + (d >> 4) * 128 + (d & 15) * 8] = pu[j];
    }
  }
  __syncthreads();

  // acc init = bias (MFMA C-in)
  f32x4 acc[8][2];
  const int mb = w * 32;                              // wave owns columns [mb, mb+32)
#pragma unroll
  for (int nt = 0; nt < 8; ++nt)
#pragma unroll
    for (int mtl = 0; mtl < 2; ++mtl)
#pragma unroll
      for (int j = 0; j < 4; ++j)
        acc[nt][mtl][j] = bf2f(biasws[(bsh << 1) + (nt * 16 + lw * 4 + j) * 128 + mb + mtl * 16 + ll16]);

  // scores += Q @ K^T  (all 128 rows x wave's 32 cols)
#pragma unroll
  for (int ks = 0; ks < 2; ++ks) {
    const int ko = (ks << 12) + lw * 8;
    bf16x8 b0 = *(const bf16x8*)&sK[ko + (mb + ll16) * 32];
    bf16x8 b1 = *(const bf16x8*)&sK[ko + (mb + 16 + ll16) * 32];
#pragma unroll
    for (int nt = 0; nt < 8; ++nt) {
      bf16x8 a = *(const bf16x8*)&sQ[ko + (nt * 16 + ll16) * 32];
      acc[nt][0] = __builtin_amdgcn_mfma_f32_16x16x32_bf16(a, b0, acc[nt][0], 0, 0, 0);
      acc[nt][1] = __builtin_amdgcn_mfma_f32_16x16x32_bf16(a, b1, acc[nt][1], 0, 0, 0);
    }
  }

  // softmax over n per column: 32 reg values + lanes {l, l^16, l^32, l^48}
  float inv[2];
#pragma unroll
  for (int mtl = 0; mtl < 2; ++mtl) {
    float mx = -3.0e38f;
#pragma unroll
    for (int nt = 0; nt < 8; ++nt)
#pragma unroll
      for (int j = 0; j < 4; ++j) mx = fmaxf(mx, acc[nt][mtl][j]);
    mx = fmaxf(mx, __shfl_xor(mx, 16));
    mx = fmaxf(mx, __shfl_xor(mx, 32));
    float sum = 0.f;
#pragma unroll
    for (int nt = 0; nt < 8; ++nt)
#pragma unroll
      for (int j = 0; j < 4; ++j) {
        float e = __expf(acc[nt][mtl][j] - mx);
        acc[nt][mtl][j] = e;
        sum += e;
      }
    sum += __shfl_xor(sum, 16);
    sum += __shfl_xor(sum, 32);
    inv[mtl] = 1.0f / sum;
  }

  __syncthreads();                                    // QK^T LDS reads done before P overwrite

  // write P [4][128][32] (group = m>>5 = w)
#pragma unroll
  for (int nt = 0; nt < 8; ++nt)
#pragma unroll
    for (int mtl = 0; mtl < 2; ++mtl)
#pragma unroll
      for (int j = 0; j < 4; ++j)
        sP[(w << 12) + (nt * 16 + lw * 4 + j) * 32 + mtl * 16 + ll16] = f2bf(acc[nt][mtl][j] * inv[mtl]);

  __syncthreads();

  // out = P @ V : wave owns output rows [w*32, w*32+32)
  f32x4 o[2][4];
#pragma unroll
  for (int i = 0; i < 2; ++i)
#pragma unroll
    for (int dt2 = 0; dt2 < 4; ++dt2)
#pragma unroll
      for (int e = 0; e < 4; ++e) o[i][dt2][e] = 0.f;
#pragma unroll
  for (int ks = 0; ks < 4; ++ks) {
    const int ko = (ks << 12) + lw * 8;
    bf16x8 a0 = *(const bf16x8*)&sP[ko + ((w * 2 + 0) * 16 + ll16) * 32];
    bf16x8 a1 = *(const bf16x8*)&sP[ko + ((w * 2 + 1) * 16 + ll16) * 32];
#pragma unroll
    for (int dt2 = 0; dt2 < 4; ++dt2) {
      bf16x8 bv2 = *(const bf16x8*)&sV[(ks * 4 + lw) * 512 + dt2 * 128 + ll16 * 8];
      o[0][dt2] = __builtin_amdgcn_mfma_f32_16x16x32_bf16(a0, bv2, o[0][dt2], 0, 0, 0);
      o[1][dt2] = __builtin_amdgcn_mfma_f32_16x16x32_bf16(a1, bv2, o[1][dt2], 0, 0, 0);
    }
  }

  // epilogue -> attn_out [b][s][n][h*64+dd] bf16
  const int ob = ((b * 14 + sI) * 128) * 512 + h * 64;
#pragma unroll
  for (int t2 = 0; t2 < 2; ++t2)
#pragma unroll
    for (int dt2 = 0; dt2 < 4; ++dt2)
#pragma unroll
      for (int j = 0; j < 4; ++j) {
        int rn = w * 32 + t2 * 16 + lw * 4 + j;
        attn_out[ob + rn * 512 + dt2 * 16 + ll16] = f2bf(o[t2][dt2][j]);
      }
}

// ---------------- output projection: out = attn_out @ Wo^T + bo (fp32 out) ----------------
__global__ __launch_bounds__(256) void out_kernel(const u16* __restrict__ attn_out, const u16* __restrict__ wobf,
                                                  const float* __restrict__ bo, float* __restrict__ out) {
  __shared__ u16 sA[8192], sB[8192];
  const int bx = blockIdx.x;                          // e-tile 0..3
  const int by = blockIdx.y;                          // row-tile 0..223
  f32x4 acc[2][8];
#pragma unroll
  for (int i = 0; i < 2; ++i)
#pragma unroll
    for (int j = 0; j < 8; ++j)
#pragma unroll
      for (int e = 0; e < 4; ++e) acc[i][j][e] = 0.f;

  gemm128(attn_out + by * 65536, wobf + bx * 65536, sA, sB, acc);

  const int t = threadIdx.x, w = t >> 6, l = t & 63;
  const int lw = l >> 4, ll16 = l & 15;
#pragma unroll
  for (int mt = 0; mt < 8; ++mt) {
    int e = bx * 128 + mt * 16 + ll16;
    float bias = bo[e];
#pragma unroll
    for (int nt = 0; nt < 2; ++nt) {
#pragma unroll
      for (int j = 0; j < 4; ++j) {
        int row = by * 128 + w * 32 + nt * 16 + lw * 4 + j;
        out[row * 512 + e] = acc[nt][mt][j] + bias;
      }
    }
  }
}

extern "C" void kernel_launch(void* const* d_in, const int* in_sizes, int n_in,
                              void* d_out, int out_size, void* d_ws, size_t ws_size,
                              hipStream_t stream) {
  (void)in_sizes; (void)n_in; (void)out_size; (void)ws_size;
  const float* q  = (const float*)d_in[0];
  const float* k  = (const float*)d_in[1];
  const float* v  = (const float*)d_in[2];
  const float* ab = (const float*)d_in[3];
  const float* Wq = (const float*)d_in[4];
  const float* bq = (const float*)d_in[5];
  const float* Wk = (const float*)d_in[6];
  const float* bk = (const float*)d_in[7];
  const float* Wv = (const float*)d_in[8];
  const float* bv = (const float*)d_in[9];
  const float* Wd = (const float*)d_in[10];
  const float* bd = (const float*)d_in[11];
  const float* Wo = (const float*)d_in[12];
  const float* bo = (const float*)d_in[13];
  float* out = (float*)d_out;

  u16* ws = (u16*)d_ws;
  u16* xT      = ws;                    // 3 * 14,680,064
  u16* qh      = ws + 44040192;         // 3 * 14,680,064
  u16* wbf     = ws + 88080384;         // 4 * 262,144
  u16* biasws  = ws;                    // overlays xT (dead after proj)
  u16* attnout = ws + 29360128;         // overlays vT (dead after proj)

  wconv_kernel<<<dim3(1024), dim3(256), 0, stream>>>(Wq, Wk, Wv, Wo, wbf);
  transpose_kernel<<<dim3(28, 8, 48), dim3(256), 0, stream>>>(q, k, v, xT);
  proj_kernel<<<dim3(4, 14, 48), dim3(256), 0, stream>>>(xT, wbf, bq, bk, bv, qh);
  bias_kernel<<<dim3(2, 128, 16), dim3(256), 0, stream>>>(ab, Wd, bd, biasws);
  attn_kernel<<<dim3(14, 8, 16), dim3(256), 0, stream>>>(qh, qh + 14680064, qh + 29360128, biasws, attnout);
  out_kernel<<<dim3(4, 224), dim3(256), 0, stream>>>(attnout, wbf + 786432, bo, out);
}

// Round 3
// 464.464 us; speedup vs baseline: 1.0283x; 1.0283x over previous
//
#include <hip/hip_runtime.h>

// MultiHeadAttention_86079734546451 — MI355X bf16 MFMA pipeline, rev 2 (resubmit;
// R2 bench failure was a container/infra error, kernel never ran).
// B=16 S=14 N=128 D=512 H=8 d=64 L=12, NS=1792.
// R1 changes: global_load_lds GEMM staging, XCD-grouped proj/out grids,
// (s,n)-ordered xT, rewritten bias kernel + [b][n][s][h][m] layout,
// attn: LDS-staged bias C-init, global_load_lds Q/K, LDS-coalesced output.

typedef unsigned short u16;
typedef __bf16 bf16x8 __attribute__((ext_vector_type(8)));
typedef float f32x4 __attribute__((ext_vector_type(4)));

#define GLDS16(g, l) __builtin_amdgcn_global_load_lds( \
    (const __attribute__((address_space(1))) void*)(g), \
    (__attribute__((address_space(3))) void*)(l), 16, 0, 0)

__device__ __forceinline__ u16 f2bf(float f) {
  unsigned u = __float_as_uint(f);
  u += 0x7fffu + ((u >> 16) & 1u);   // RTNE (finite inputs)
  return (u16)(u >> 16);
}
__device__ __forceinline__ float bf2f(u16 b) {
  return __uint_as_float(((unsigned)b) << 16);
}

// ---------------- weight convert: fp32 -> bf16, Wq scaled by 1/8 ----------------
__global__ __launch_bounds__(256) void wconv_kernel(const float* __restrict__ Wq, const float* __restrict__ Wk,
                                                    const float* __restrict__ Wv, const float* __restrict__ Wo,
                                                    u16* __restrict__ wbf) {
  int idx = (blockIdx.x * 256 + threadIdx.x) * 4;
  int m = idx >> 18;
  int r = idx & 262143;
  const float* src = (m == 0) ? Wq : (m == 1) ? Wk : (m == 2) ? Wv : Wo;
  float sc = (m == 0) ? 0.125f : 1.0f;
  float4 v = *(const float4*)&src[r];
  ushort4 o;
  o.x = f2bf(v.x * sc); o.y = f2bf(v.y * sc); o.z = f2bf(v.z * sc); o.w = f2bf(v.w * sc);
  *(ushort4*)&wbf[idx] = o;
}

// ------- transpose q/k/v: [b][D][n*14+s] f32 -> xT [b][s*128+n][D] bf16 -------
__global__ __launch_bounds__(256) void transpose_kernel(const float* __restrict__ q, const float* __restrict__ k,
                                                        const float* __restrict__ v, u16* __restrict__ xT) {
  __shared__ u16 tile[64 * 76];
  const int nst = blockIdx.x;                         // 0..27 (source-col tile)
  const int dt  = blockIdx.y;                         // 0..7
  const int z   = blockIdx.z;
  const int which = z >> 4, b = z & 15;
  const float* src = (which == 0) ? q : (which == 1) ? k : v;
  u16* dst = xT + which * 14680064;
  const int t = threadIdx.x;
  const int c4 = t & 15, r0 = t >> 4;
#pragma unroll
  for (int it = 0; it < 4; ++it) {
    int r = r0 + it * 16;
    float4 f = *(const float4*)&src[(b * 512 + dt * 64 + r) * 1792 + nst * 64 + c4 * 4];
    ushort4 o; o.x = f2bf(f.x); o.y = f2bf(f.y); o.z = f2bf(f.z); o.w = f2bf(f.w);
    *(ushort4*)&tile[r * 76 + c4 * 4] = o;
  }
  __syncthreads();
  const int dq = t & 15, nr0 = t >> 4;
#pragma unroll
  for (int it = 0; it < 4; ++it) {
    int nr = nr0 + it * 16;
    unsigned c = nst * 64 + nr;                       // source col = n*14+s
    unsigned n = c / 14u, sI = c - n * 14u;
    ushort4 o;
    o.x = tile[(dq * 4 + 0) * 76 + nr];
    o.y = tile[(dq * 4 + 1) * 76 + nr];
    o.z = tile[(dq * 4 + 2) * 76 + nr];
    o.w = tile[(dq * 4 + 3) * 76 + nr];
    *(ushort4*)&dst[(b * 1792 + sI * 128 + n) * 512 + dt * 64 + dq * 4] = o;
  }
}

// ------- 128x128x512 bf16 GEMM body, global_load_lds staging -------
// LDS tile layout (16B-chunk index c): byte = c*16; global chunk:
//   row = (c>>2)&127, g = ((c>>9)<<2)|(c&3), src = row*512 + kb*64 + g*8 (u16)
// => LDS u16 offset c*8 == ((g>>2)<<12) + row*32 + (g&3)*8 (the [kk][128][32] layout)
__device__ __forceinline__ void gemm128(const u16* __restrict__ Ag, const u16* __restrict__ Bg,
                                        u16* sA, u16* sB, f32x4 acc[2][8]) {
  const int t = threadIdx.x;
  const int w = t >> 6, l = t & 63;
  const int lw = l >> 4, ll16 = l & 15;
  for (int kb = 0; kb < 8; ++kb) {
#pragma unroll
    for (int it = 0; it < 4; ++it) {
      int c = w * 64 + it * 256 + l;
      int row = (c >> 2) & 127;
      int g = ((c >> 9) << 2) | (c & 3);
      int go = row * 512 + kb * 64 + g * 8;
      GLDS16(Ag + go, sA + (w * 64 + it * 256) * 8);
      GLDS16(Bg + go, sB + (w * 64 + it * 256) * 8);
    }
    __syncthreads();
#pragma unroll
    for (int kk = 0; kk < 2; ++kk) {
      const int ko = (kk << 12) + lw * 8;
      bf16x8 a0 = *(const bf16x8*)&sA[ko + (w * 32 + ll16) * 32];
      bf16x8 a1 = *(const bf16x8*)&sA[ko + (w * 32 + 16 + ll16) * 32];
#pragma unroll
      for (int mt = 0; mt < 8; ++mt) {
        bf16x8 bb = *(const bf16x8*)&sB[ko + (mt * 16 + ll16) * 32];
        acc[0][mt] = __builtin_amdgcn_mfma_f32_16x16x32_bf16(a0, bb, acc[0][mt], 0, 0, 0);
        acc[1][mt] = __builtin_amdgcn_mfma_f32_16x16x32_bf16(a1, bb, acc[1][mt], 0, 0, 0);
      }
    }
    __syncthreads();
  }
}

// ------- QKV projection, XCD-grouped grid (2688 blocks) -------
__global__ __launch_bounds__(256) void proj_kernel(const u16* __restrict__ xT, const u16* __restrict__ wbf,
                                                   const float* __restrict__ bq, const float* __restrict__ bk,
                                                   const float* __restrict__ bv, u16* __restrict__ qh) {
  __shared__ u16 sA[8192], sB[8192];
  const unsigned u = blockIdx.x;
  const int xcd = u & 7, slot = u >> 3;               // 336 slots/xcd
  const int bx = slot & 3;
  const int gidx = xcd * 84 + (slot >> 2);            // 0..671 = A-tile id
  const int by = gidx % 14;                           // == s
  const int z  = gidx / 14;                           // p*16+b
  const int p = z >> 4, b = z & 15;
  const u16* Ag = xT + p * 14680064 + b * 917504 + by * 65536;
  const u16* Bg = wbf + p * 262144 + bx * 65536;
  const float* bvec = (p == 0) ? bq : (p == 1) ? bk : bv;
  const float bscale = (p == 0) ? 0.125f : 1.0f;
  u16* outp = qh + p * 14680064;

  f32x4 acc[2][8];
#pragma unroll
  for (int i = 0; i < 2; ++i)
#pragma unroll
    for (int j = 0; j < 8; ++j)
#pragma unroll
      for (int e = 0; e < 4; ++e) acc[i][j][e] = 0.f;

  gemm128(Ag, Bg, sA, sB, acc);

  const int t = threadIdx.x, w = t >> 6, l = t & 63;
  const int lw = l >> 4, ll16 = l & 15;
#pragma unroll
  for (int mt = 0; mt < 8; ++mt) {
    int e = bx * 128 + mt * 16 + ll16;
    float bias = bvec[e] * bscale;
    int hh = e >> 6, dd = e & 63;
#pragma unroll
    for (int nt = 0; nt < 2; ++nt) {
#pragma unroll
      for (int j = 0; j < 4; ++j) {
        int n = w * 32 + nt * 16 + lw * 4 + j;        // local row == n, s == by
        outp[(((b * 14 + by) * 8 + hh) << 13) + n * 64 + dd] = f2bf(acc[nt][mt][j] + bias);
      }
    }
  }
}

// ------- bias: ab[b,l,n,m,h] @ Wd[s,l] + bd -> bias2 [b][n][s][h][m] bf16 -------
__global__ __launch_bounds__(256) void bias_kernel(const float* __restrict__ ab, const float* __restrict__ Wd,
                                                   const float* __restrict__ bd, u16* __restrict__ bias2) {
  __shared__ float abt[12 * 1056];                    // [l][h][m]: l*1056 + h*132 + m
  const int n = blockIdx.x;                           // 0..127 (score row)
  const int b = blockIdx.y;                           // 0..15
  const int t = threadIdx.x;
#pragma unroll
  for (int it = 0; it < 12; ++it) {
    int i = t + 256 * it;                             // float4 chunk 0..3071
    int lI = i >> 8, rem = i & 255;
    int m = rem >> 1, hq = rem & 1;
    float4 f = *(const float4*)&ab[(((b * 12 + lI) * 128 + n) * 128 + m) * 8 + hq * 4];
    float* dstp = &abt[lI * 1056 + (hq * 4) * 132 + m];
    dstp[0] = f.x; dstp[132] = f.y; dstp[264] = f.z; dstp[396] = f.w;
  }
  __syncthreads();
  const int h = t >> 5, m0 = (t & 31) * 4;
  float4 f4[12];
#pragma unroll
  for (int lI = 0; lI < 12; ++lI) f4[lI] = *(const float4*)&abt[lI * 1056 + h * 132 + m0];
  u16* outb = bias2 + (b * 128 + n) * 14336 + h * 128 + m0;
#pragma unroll
  for (int sI = 0; sI < 14; ++sI) {
    float r0 = bd[sI], r1 = bd[sI], r2 = bd[sI], r3 = bd[sI];
#pragma unroll
    for (int lI = 0; lI < 12; ++lI) {
      float wv = Wd[sI * 12 + lI];
      r0 += wv * f4[lI].x; r1 += wv * f4[lI].y; r2 += wv * f4[lI].z; r3 += wv * f4[lI].w;
    }
    ushort4 o; o.x = f2bf(r0); o.y = f2bf(r1); o.z = f2bf(r2); o.w = f2bf(r3);
    *(ushort4*)&outb[sI * 1024] = o;
  }
}

// ------- attention: per (b,s,h); softmax over n (rows) per column m -------
__global__ __launch_bounds__(256) void attn_kernel(const u16* __restrict__ qh, const u16* __restrict__ kh,
                                                   const u16* __restrict__ vh, const u16* __restrict__ bias2,
                                                   u16* __restrict__ attn_out) {
  __shared__ u16 smem[25600];                         // 50 KB
  u16* sBias = smem;                                  // [128][136] u16 (34816 B)
  u16* sQ = smem;                                     // [2][128][32] after C-init
  u16* sK = smem + 8192;
  u16* sP = smem;                                     // [4][128][32] after QK^T
  u16* sOut = smem;                                   // [128][72] after PV
  u16* sV = smem + 17408;                             // B-frag layout (16 KB)

  const int sI = blockIdx.x, h = blockIdx.y, b = blockIdx.z;
  const int t = threadIdx.x, w = t >> 6, l = t & 63;
  const int lw = l >> 4, ll16 = l & 15;
  const int bsh = ((b * 14 + sI) * 8 + h) << 13;      // *8192

  // stage V into PV B-fragment layout (register path)
#pragma unroll
  for (int it = 0; it < 4; ++it) {
    int m = (t >> 3) + 32 * it;
    int dd0 = (t & 7) * 8;
    uint4 uu = *(const uint4*)&vh[bsh + m * 64 + dd0];
    const u16* pu = (const u16*)&uu;
    int mo = (m >> 3) * 512 + (m & 7);
#pragma unroll
    for (int j = 0; j < 8; ++j) {
      int d = dd0 + j;
      sV[mo + (d >> 4) * 128 + (d & 15) * 8] = pu[j];
    }
  }
  // stage bias tile [128 n][128 m] -> sBias [128][136]
  {
    const u16* bb = bias2 + (b * 128) * 14336 + sI * 1024 + h * 128;
#pragma unroll
    for (int it = 0; it < 8; ++it) {
      int c = t + 256 * it;                           // 0..2047
      int n = c >> 4, mc = c & 15;
      uint4 uu = *(const uint4*)&bb[n * 14336 + mc * 8];
      *(uint4*)&sBias[n * 136 + mc * 8] = uu;
    }
  }
  __syncthreads();

  // C-init = bias
  f32x4 acc[8][2];
  const int mb = w * 32;
#pragma unroll
  for (int nt = 0; nt < 8; ++nt)
#pragma unroll
    for (int mtl = 0; mtl < 2; ++mtl)
#pragma unroll
      for (int j = 0; j < 4; ++j)
        acc[nt][mtl][j] = bf2f(sBias[(nt * 16 + lw * 4 + j) * 136 + mb + mtl * 16 + ll16]);
  __syncthreads();                                    // bias reads done before Q/K overwrite

  // stage Q, K via global_load_lds into [2][128][32]
#pragma unroll
  for (int it = 0; it < 4; ++it) {
    int c = w * 64 + it * 256 + l;
    int row = (c >> 2) & 127;
    int g = ((c >> 9) << 2) | (c & 3);
    int go = row * 64 + g * 8;
    GLDS16(qh + bsh + go, sQ + (w * 64 + it * 256) * 8);
    GLDS16(kh + bsh + go, sK + (w * 64 + it * 256) * 8);
  }
  __syncthreads();

  // scores += Q @ K^T
#pragma unroll
  for (int ks = 0; ks < 2; ++ks) {
    const int ko = (ks << 12) + lw * 8;
    bf16x8 b0 = *(const bf16x8*)&sK[ko + (mb + ll16) * 32];
    bf16x8 b1 = *(const bf16x8*)&sK[ko + (mb + 16 + ll16) * 32];
#pragma unroll
    for (int nt = 0; nt < 8; ++nt) {
      bf16x8 a = *(const bf16x8*)&sQ[ko + (nt * 16 + ll16) * 32];
      acc[nt][0] = __builtin_amdgcn_mfma_f32_16x16x32_bf16(a, b0, acc[nt][0], 0, 0, 0);
      acc[nt][1] = __builtin_amdgcn_mfma_f32_16x16x32_bf16(a, b1, acc[nt][1], 0, 0, 0);
    }
  }

  // softmax over n per column m (32 regs + lanes {l, l^16, l^32, l^48})
  float inv[2];
#pragma unroll
  for (int mtl = 0; mtl < 2; ++mtl) {
    float mx = -3.0e38f;
#pragma unroll
    for (int nt = 0; nt < 8; ++nt)
#pragma unroll
      for (int j = 0; j < 4; ++j) mx = fmaxf(mx, acc[nt][mtl][j]);
    mx = fmaxf(mx, __shfl_xor(mx, 16));
    mx = fmaxf(mx, __shfl_xor(mx, 32));
    float sum = 0.f;
#pragma unroll
    for (int nt = 0; nt < 8; ++nt)
#pragma unroll
      for (int j = 0; j < 4; ++j) {
        float e = __expf(acc[nt][mtl][j] - mx);
        acc[nt][mtl][j] = e;
        sum += e;
      }
    sum += __shfl_xor(sum, 16);
    sum += __shfl_xor(sum, 32);
    inv[mtl] = 1.0f / sum;
  }
  __syncthreads();                                    // QK^T LDS reads done

  // write P [4][128][32]
#pragma unroll
  for (int nt = 0; nt < 8; ++nt)
#pragma unroll
    for (int mtl = 0; mtl < 2; ++mtl)
#pragma unroll
      for (int j = 0; j < 4; ++j)
        sP[(w << 12) + (nt * 16 + lw * 4 + j) * 32 + mtl * 16 + ll16] = f2bf(acc[nt][mtl][j] * inv[mtl]);
  __syncthreads();

  // out = P @ V : wave owns output rows [w*32, w*32+32)
  f32x4 o[2][4];
#pragma unroll
  for (int i = 0; i < 2; ++i)
#pragma unroll
    for (int dt2 = 0; dt2 < 4; ++dt2)
#pragma unroll
      for (int e = 0; e < 4; ++e) o[i][dt2][e] = 0.f;
#pragma unroll
  for (int ks = 0; ks < 4; ++ks) {
    const int ko = (ks << 12) + lw * 8;
    bf16x8 a0 = *(const bf16x8*)&sP[ko + ((w * 2 + 0) * 16 + ll16) * 32];
    bf16x8 a1 = *(const bf16x8*)&sP[ko + ((w * 2 + 1) * 16 + ll16) * 32];
#pragma unroll
    for (int dt2 = 0; dt2 < 4; ++dt2) {
      bf16x8 bv2 = *(const bf16x8*)&sV[(ks * 4 + lw) * 512 + dt2 * 128 + ll16 * 8];
      o[0][dt2] = __builtin_amdgcn_mfma_f32_16x16x32_bf16(a0, bv2, o[0][dt2], 0, 0, 0);
      o[1][dt2] = __builtin_amdgcn_mfma_f32_16x16x32_bf16(a1, bv2, o[1][dt2], 0, 0, 0);
    }
  }
  __syncthreads();                                    // sP reads done before sOut overwrite

  // stage output tile [128 n][64 d] -> sOut[128][72], then coalesced copy
#pragma unroll
  for (int t2 = 0; t2 < 2; ++t2)
#pragma unroll
    for (int dt2 = 0; dt2 < 4; ++dt2)
#pragma unroll
      for (int j = 0; j < 4; ++j) {
        int rn = w * 32 + t2 * 16 + lw * 4 + j;
        sOut[rn * 72 + dt2 * 16 + ll16] = f2bf(o[t2][dt2][j]);
      }
  __syncthreads();
  const int ob = ((b * 14 + sI) * 128) * 512 + h * 64;
#pragma unroll
  for (int i = 0; i < 4; ++i) {
    int c = t + 256 * i;                              // 0..1023
    int row = c >> 3, ch = c & 7;
    uint4 uu = *(const uint4*)&sOut[row * 72 + ch * 8];
    *(uint4*)&attn_out[ob + row * 512 + ch * 8] = uu;
  }
}

// ------- output projection: out = attn_out @ Wo^T + bo (fp32), XCD-grouped -------
__global__ __launch_bounds__(256) void out_kernel(const u16* __restrict__ attn_out, const u16* __restrict__ wobf,
                                                  const float* __restrict__ bo, float* __restrict__ out) {
  __shared__ u16 sA[8192], sB[8192];
  const unsigned u = blockIdx.x;
  const int xcd = u & 7, slot = u >> 3;               // 112 slots/xcd
  const int bx = slot & 3;
  const int by = xcd * 28 + (slot >> 2);              // 0..223
  f32x4 acc[2][8];
#pragma unroll
  for (int i = 0; i < 2; ++i)
#pragma unroll
    for (int j = 0; j < 8; ++j)
#pragma unroll
      for (int e = 0; e < 4; ++e) acc[i][j][e] = 0.f;

  gemm128(attn_out + by * 65536, wobf + bx * 65536, sA, sB, acc);

  const int t = threadIdx.x, w = t >> 6, l = t & 63;
  const int lw = l >> 4, ll16 = l & 15;
#pragma unroll
  for (int mt = 0; mt < 8; ++mt) {
    int e = bx * 128 + mt * 16 + ll16;
    float bias = bo[e];
#pragma unroll
    for (int nt = 0; nt < 2; ++nt) {
#pragma unroll
      for (int j = 0; j < 4; ++j) {
        int row = by * 128 + w * 32 + nt * 16 + lw * 4 + j;
        out[row * 512 + e] = acc[nt][mt][j] + bias;
      }
    }
  }
}

extern "C" void kernel_launch(void* const* d_in, const int* in_sizes, int n_in,
                              void* d_out, int out_size, void* d_ws, size_t ws_size,
                              hipStream_t stream) {
  (void)in_sizes; (void)n_in; (void)out_size; (void)ws_size;
  const float* q  = (const float*)d_in[0];
  const float* k  = (const float*)d_in[1];
  const float* v  = (const float*)d_in[2];
  const float* ab = (const float*)d_in[3];
  const float* Wq = (const float*)d_in[4];
  const float* bq = (const float*)d_in[5];
  const float* Wk = (const float*)d_in[6];
  const float* bk = (const float*)d_in[7];
  const float* Wv = (const float*)d_in[8];
  const float* bv = (const float*)d_in[9];
  const float* Wd = (const float*)d_in[10];
  const float* bd = (const float*)d_in[11];
  const float* Wo = (const float*)d_in[12];
  const float* bo = (const float*)d_in[13];
  float* out = (float*)d_out;

  u16* ws = (u16*)d_ws;
  u16* xT      = ws;                    // 3 * 14,680,064
  u16* qh      = ws + 44040192;         // 3 * 14,680,064
  u16* wbf     = ws + 88080384;         // 4 * 262,144
  u16* bias2   = ws;                    // overlays xT (dead after proj): 29,360,128
  u16* attnout = ws + 29360128;         // 14,680,064

  wconv_kernel<<<dim3(1024), dim3(256), 0, stream>>>(Wq, Wk, Wv, Wo, wbf);
  transpose_kernel<<<dim3(28, 8, 48), dim3(256), 0, stream>>>(q, k, v, xT);
  proj_kernel<<<dim3(2688), dim3(256), 0, stream>>>(xT, wbf, bq, bk, bv, qh);
  bias_kernel<<<dim3(128, 16), dim3(256), 0, stream>>>(ab, Wd, bd, bias2);
  attn_kernel<<<dim3(14, 8, 16), dim3(256), 0, stream>>>(qh, qh + 14680064, qh + 29360128, bias2, attnout);
  out_kernel<<<dim3(896), dim3(256), 0, stream>>>(attnout, wbf + 786432, bo, out);
}

// Round 4
// 458.012 us; speedup vs baseline: 1.0428x; 1.0141x over previous
//
#include <hip/hip_runtime.h>

// MultiHeadAttention_86079734546451 — MI355X bf16 MFMA pipeline, rev 3.
// B=16 S=14 N=128 D=512 H=8 d=64 L=12, NS=1792.
// R3 change: GEMM body (proj/out) -> double-buffered 2-phase with raw s_barrier
// + counted s_waitcnt vmcnt(8) (T3-minimal). Loads for step k+1 stay in flight
// across the barrier; their latency hides under step k's ds_read+MFMA.

typedef unsigned short u16;
typedef __bf16 bf16x8 __attribute__((ext_vector_type(8)));
typedef float f32x4 __attribute__((ext_vector_type(4)));

#define GLDS16(g, l) __builtin_amdgcn_global_load_lds( \
    (const __attribute__((address_space(1))) void*)(g), \
    (__attribute__((address_space(3))) void*)(l), 16, 0, 0)

__device__ __forceinline__ u16 f2bf(float f) {
  unsigned u = __float_as_uint(f);
  u += 0x7fffu + ((u >> 16) & 1u);   // RTNE (finite inputs)
  return (u16)(u >> 16);
}
__device__ __forceinline__ float bf2f(u16 b) {
  return __uint_as_float(((unsigned)b) << 16);
}

// ---------------- weight convert: fp32 -> bf16, Wq scaled by 1/8 ----------------
__global__ __launch_bounds__(256) void wconv_kernel(const float* __restrict__ Wq, const float* __restrict__ Wk,
                                                    const float* __restrict__ Wv, const float* __restrict__ Wo,
                                                    u16* __restrict__ wbf) {
  int idx = (blockIdx.x * 256 + threadIdx.x) * 4;
  int m = idx >> 18;
  int r = idx & 262143;
  const float* src = (m == 0) ? Wq : (m == 1) ? Wk : (m == 2) ? Wv : Wo;
  float sc = (m == 0) ? 0.125f : 1.0f;
  float4 v = *(const float4*)&src[r];
  ushort4 o;
  o.x = f2bf(v.x * sc); o.y = f2bf(v.y * sc); o.z = f2bf(v.z * sc); o.w = f2bf(v.w * sc);
  *(ushort4*)&wbf[idx] = o;
}

// ------- transpose q/k/v: [b][D][n*14+s] f32 -> xT [b][s*128+n][D] bf16 -------
__global__ __launch_bounds__(256) void transpose_kernel(const float* __restrict__ q, const float* __restrict__ k,
                                                        const float* __restrict__ v, u16* __restrict__ xT) {
  __shared__ u16 tile[64 * 76];
  const int nst = blockIdx.x;                         // 0..27 (source-col tile)
  const int dt  = blockIdx.y;                         // 0..7
  const int z   = blockIdx.z;
  const int which = z >> 4, b = z & 15;
  const float* src = (which == 0) ? q : (which == 1) ? k : v;
  u16* dst = xT + which * 14680064;
  const int t = threadIdx.x;
  const int c4 = t & 15, r0 = t >> 4;
#pragma unroll
  for (int it = 0; it < 4; ++it) {
    int r = r0 + it * 16;
    float4 f = *(const float4*)&src[(b * 512 + dt * 64 + r) * 1792 + nst * 64 + c4 * 4];
    ushort4 o; o.x = f2bf(f.x); o.y = f2bf(f.y); o.z = f2bf(f.z); o.w = f2bf(f.w);
    *(ushort4*)&tile[r * 76 + c4 * 4] = o;
  }
  __syncthreads();
  const int dq = t & 15, nr0 = t >> 4;
#pragma unroll
  for (int it = 0; it < 4; ++it) {
    int nr = nr0 + it * 16;
    unsigned c = nst * 64 + nr;                       // source col = n*14+s
    unsigned n = c / 14u, sI = c - n * 14u;
    ushort4 o;
    o.x = tile[(dq * 4 + 0) * 76 + nr];
    o.y = tile[(dq * 4 + 1) * 76 + nr];
    o.z = tile[(dq * 4 + 2) * 76 + nr];
    o.w = tile[(dq * 4 + 3) * 76 + nr];
    *(ushort4*)&dst[(b * 1792 + sI * 128 + n) * 512 + dt * 64 + dq * 4] = o;
  }
}

// ------- 128x128x512 bf16 GEMM, double-buffered 2-phase, counted vmcnt -------
// LDS view per buffer: [kk][128][32] u16; staged via global_load_lds (wave-uniform
// dest base + lane*16; inverse permutation carried on the global address).
__device__ __forceinline__ void stageAB(const u16* __restrict__ Ag, const u16* __restrict__ Bg,
                                        int kb, u16* sA, u16* sB, int w, int l) {
#pragma unroll
  for (int it = 0; it < 4; ++it) {
    int c = w * 64 + it * 256 + l;                    // chunk id; LDS byte = c*16
    int row = (c >> 2) & 127;
    int g = ((c >> 9) << 2) | (c & 3);
    int go = row * 512 + kb * 64 + g * 8;
    GLDS16(Ag + go, sA + (w * 64 + it * 256) * 8);    // HW adds lane*16
    GLDS16(Bg + go, sB + (w * 64 + it * 256) * 8);
  }
}

__device__ __forceinline__ void mfma_step(const u16* sA, const u16* sB, f32x4 acc[2][8],
                                          int w, int lw, int ll16) {
#pragma unroll
  for (int kk = 0; kk < 2; ++kk) {
    const int ko = (kk << 12) + lw * 8;
    bf16x8 a0 = *(const bf16x8*)&sA[ko + (w * 32 + ll16) * 32];
    bf16x8 a1 = *(const bf16x8*)&sA[ko + (w * 32 + 16 + ll16) * 32];
#pragma unroll
    for (int mt = 0; mt < 8; ++mt) {
      bf16x8 bb = *(const bf16x8*)&sB[ko + (mt * 16 + ll16) * 32];
      acc[0][mt] = __builtin_amdgcn_mfma_f32_16x16x32_bf16(a0, bb, acc[0][mt], 0, 0, 0);
      acc[1][mt] = __builtin_amdgcn_mfma_f32_16x16x32_bf16(a1, bb, acc[1][mt], 0, 0, 0);
    }
  }
}

__device__ __forceinline__ void gemm128_db(const u16* __restrict__ Ag, const u16* __restrict__ Bg,
                                           u16* sm, f32x4 acc[2][8]) {
  u16* sA0 = sm;            u16* sB0 = sm + 8192;
  u16* sA1 = sm + 16384;    u16* sB1 = sm + 24576;
  const int t = threadIdx.x;
  const int w = t >> 6, l = t & 63;
  const int lw = l >> 4, ll16 = l & 15;

  stageAB(Ag, Bg, 0, sA0, sB0, w, l);                 // prologue: buf0 <- step 0
#pragma unroll
  for (int kb = 0; kb < 8; ++kb) {
    const u16* cA = (kb & 1) ? sA1 : sA0;
    const u16* cB = (kb & 1) ? sB1 : sB0;
    if (kb < 7) {
      stageAB(Ag, Bg, kb + 1, (kb & 1) ? sA0 : sA1, (kb & 1) ? sB0 : sB1, w, l);
      asm volatile("s_waitcnt vmcnt(8)" ::: "memory"); // drain step-kb batch; keep kb+1 in flight
    } else {
      asm volatile("s_waitcnt vmcnt(0)" ::: "memory");
    }
    __builtin_amdgcn_s_barrier();
    __builtin_amdgcn_sched_barrier(0);
    mfma_step(cA, cB, acc, w, lw, ll16);
    __builtin_amdgcn_s_barrier();                     // readers done before buf reuse
  }
}

// ------- QKV projection, XCD-grouped grid (2688 blocks) -------
__global__ __launch_bounds__(256) void proj_kernel(const u16* __restrict__ xT, const u16* __restrict__ wbf,
                                                   const float* __restrict__ bq, const float* __restrict__ bk,
                                                   const float* __restrict__ bv, u16* __restrict__ qh) {
  __shared__ u16 sm[32768];                           // 64 KB: 2 x (A,B)
  const unsigned u = blockIdx.x;
  const int xcd = u & 7, slot = u >> 3;               // 336 slots/xcd
  const int bx = slot & 3;
  const int gidx = xcd * 84 + (slot >> 2);            // 0..671 = A-tile id
  const int by = gidx % 14;                           // == s
  const int z  = gidx / 14;                           // p*16+b
  const int p = z >> 4, b = z & 15;
  const u16* Ag = xT + p * 14680064 + b * 917504 + by * 65536;
  const u16* Bg = wbf + p * 262144 + bx * 65536;
  const float* bvec = (p == 0) ? bq : (p == 1) ? bk : bv;
  const float bscale = (p == 0) ? 0.125f : 1.0f;
  u16* outp = qh + p * 14680064;

  f32x4 acc[2][8];
#pragma unroll
  for (int i = 0; i < 2; ++i)
#pragma unroll
    for (int j = 0; j < 8; ++j)
#pragma unroll
      for (int e = 0; e < 4; ++e) acc[i][j][e] = 0.f;

  gemm128_db(Ag, Bg, sm, acc);

  const int t = threadIdx.x, w = t >> 6, l = t & 63;
  const int lw = l >> 4, ll16 = l & 15;
#pragma unroll
  for (int mt = 0; mt < 8; ++mt) {
    int e = bx * 128 + mt * 16 + ll16;
    float bias = bvec[e] * bscale;
    int hh = e >> 6, dd = e & 63;
#pragma unroll
    for (int nt = 0; nt < 2; ++nt) {
#pragma unroll
      for (int j = 0; j < 4; ++j) {
        int n = w * 32 + nt * 16 + lw * 4 + j;        // local row == n, s == by
        outp[(((b * 14 + by) * 8 + hh) << 13) + n * 64 + dd] = f2bf(acc[nt][mt][j] + bias);
      }
    }
  }
}

// ------- bias: ab[b,l,n,m,h] @ Wd[s,l] + bd -> bias2 [b][n][s][h][m] bf16 -------
__global__ __launch_bounds__(256) void bias_kernel(const float* __restrict__ ab, const float* __restrict__ Wd,
                                                   const float* __restrict__ bd, u16* __restrict__ bias2) {
  __shared__ float abt[12 * 1056];                    // [l][h][m]: l*1056 + h*132 + m
  const int n = blockIdx.x;                           // 0..127 (score row)
  const int b = blockIdx.y;                           // 0..15
  const int t = threadIdx.x;
#pragma unroll
  for (int it = 0; it < 12; ++it) {
    int i = t + 256 * it;                             // float4 chunk 0..3071
    int lI = i >> 8, rem = i & 255;
    int m = rem >> 1, hq = rem & 1;
    float4 f = *(const float4*)&ab[(((b * 12 + lI) * 128 + n) * 128 + m) * 8 + hq * 4];
    float* dstp = &abt[lI * 1056 + (hq * 4) * 132 + m];
    dstp[0] = f.x; dstp[132] = f.y; dstp[264] = f.z; dstp[396] = f.w;
  }
  __syncthreads();
  const int h = t >> 5, m0 = (t & 31) * 4;
  float4 f4[12];
#pragma unroll
  for (int lI = 0; lI < 12; ++lI) f4[lI] = *(const float4*)&abt[lI * 1056 + h * 132 + m0];
  u16* outb = bias2 + (b * 128 + n) * 14336 + h * 128 + m0;
#pragma unroll
  for (int sI = 0; sI < 14; ++sI) {
    float r0 = bd[sI], r1 = bd[sI], r2 = bd[sI], r3 = bd[sI];
#pragma unroll
    for (int lI = 0; lI < 12; ++lI) {
      float wv = Wd[sI * 12 + lI];
      r0 += wv * f4[lI].x; r1 += wv * f4[lI].y; r2 += wv * f4[lI].z; r3 += wv * f4[lI].w;
    }
    ushort4 o; o.x = f2bf(r0); o.y = f2bf(r1); o.z = f2bf(r2); o.w = f2bf(r3);
    *(ushort4*)&outb[sI * 1024] = o;
  }
}

// ------- attention: per (b,s,h); softmax over n (rows) per column m -------
__global__ __launch_bounds__(256) void attn_kernel(const u16* __restrict__ qh, const u16* __restrict__ kh,
                                                   const u16* __restrict__ vh, const u16* __restrict__ bias2,
                                                   u16* __restrict__ attn_out) {
  __shared__ u16 smem[25600];                         // 50 KB
  u16* sBias = smem;                                  // [128][136] u16 (34816 B)
  u16* sQ = smem;                                     // [2][128][32] after C-init
  u16* sK = smem + 8192;
  u16* sP = smem;                                     // [4][128][32] after QK^T
  u16* sOut = smem;                                   // [128][72] after PV
  u16* sV = smem + 17408;                             // B-frag layout (16 KB)

  const int sI = blockIdx.x, h = blockIdx.y, b = blockIdx.z;
  const int t = threadIdx.x, w = t >> 6, l = t & 63;
  const int lw = l >> 4, ll16 = l & 15;
  const int bsh = ((b * 14 + sI) * 8 + h) << 13;      // *8192

  // stage V into PV B-fragment layout (register path)
#pragma unroll
  for (int it = 0; it < 4; ++it) {
    int m = (t >> 3) + 32 * it;
    int dd0 = (t & 7) * 8;
    uint4 uu = *(const uint4*)&vh[bsh + m * 64 + dd0];
    const u16* pu = (const u16*)&uu;
    int mo = (m >> 3) * 512 + (m & 7);
#pragma unroll
    for (int j = 0; j < 8; ++j) {
      int d = dd0 + j;
      sV[mo + (d >> 4) * 128 + (d & 15) * 8] = pu[j];
    }
  }
  // stage bias tile [128 n][128 m] -> sBias [128][136]
  {
    const u16* bb = bias2 + (b * 128) * 14336 + sI * 1024 + h * 128;
#pragma unroll
    for (int it = 0; it < 8; ++it) {
      int c = t + 256 * it;                           // 0..2047
      int n = c >> 4, mc = c & 15;
      uint4 uu = *(const uint4*)&bb[n * 14336 + mc * 8];
      *(uint4*)&sBias[n * 136 + mc * 8] = uu;
    }
  }
  __syncthreads();

  // C-init = bias
  f32x4 acc[8][2];
  const int mb = w * 32;
#pragma unroll
  for (int nt = 0; nt < 8; ++nt)
#pragma unroll
    for (int mtl = 0; mtl < 2; ++mtl)
#pragma unroll
      for (int j = 0; j < 4; ++j)
        acc[nt][mtl][j] = bf2f(sBias[(nt * 16 + lw * 4 + j) * 136 + mb + mtl * 16 + ll16]);
  __syncthreads();                                    // bias reads done before Q/K overwrite

  // stage Q, K via global_load_lds into [2][128][32]
#pragma unroll
  for (int it = 0; it < 4; ++it) {
    int c = w * 64 + it * 256 + l;
    int row = (c >> 2) & 127;
    int g = ((c >> 9) << 2) | (c & 3);
    int go = row * 64 + g * 8;
    GLDS16(qh + bsh + go, sQ + (w * 64 + it * 256) * 8);
    GLDS16(kh + bsh + go, sK + (w * 64 + it * 256) * 8);
  }
  __syncthreads();

  // scores += Q @ K^T
#pragma unroll
  for (int ks = 0; ks < 2; ++ks) {
    const int ko = (ks << 12) + lw * 8;
    bf16x8 b0 = *(const bf16x8*)&sK[ko + (mb + ll16) * 32];
    bf16x8 b1 = *(const bf16x8*)&sK[ko + (mb + 16 + ll16) * 32];
#pragma unroll
    for (int nt = 0; nt < 8; ++nt) {
      bf16x8 a = *(const bf16x8*)&sQ[ko + (nt * 16 + ll16) * 32];
      acc[nt][0] = __builtin_amdgcn_mfma_f32_16x16x32_bf16(a, b0, acc[nt][0], 0, 0, 0);
      acc[nt][1] = __builtin_amdgcn_mfma_f32_16x16x32_bf16(a, b1, acc[nt][1], 0, 0, 0);
    }
  }

  // softmax over n per column m (32 regs + lanes {l, l^16, l^32, l^48})
  float inv[2];
#pragma unroll
  for (int mtl = 0; mtl < 2; ++mtl) {
    float mx = -3.0e38f;
#pragma unroll
    for (int nt = 0; nt < 8; ++nt)
#pragma unroll
      for (int j = 0; j < 4; ++j) mx = fmaxf(mx, acc[nt][mtl][j]);
    mx = fmaxf(mx, __shfl_xor(mx, 16));
    mx = fmaxf(mx, __shfl_xor(mx, 32));
    float sum = 0.f;
#pragma unroll
    for (int nt = 0; nt < 8; ++nt)
#pragma unroll
      for (int j = 0; j < 4; ++j) {
        float e = __expf(acc[nt][mtl][j] - mx);
        acc[nt][mtl][j] = e;
        sum += e;
      }
    sum += __shfl_xor(sum, 16);
    sum += __shfl_xor(sum, 32);
    inv[mtl] = 1.0f / sum;
  }
  __syncthreads();                                    // QK^T LDS reads done

  // write P [4][128][32]
#pragma unroll
  for (int nt = 0; nt < 8; ++nt)
#pragma unroll
    for (int mtl = 0; mtl < 2; ++mtl)
#pragma unroll
      for (int j = 0; j < 4; ++j)
        sP[(w << 12) + (nt * 16 + lw * 4 + j) * 32 + mtl * 16 + ll16] = f2bf(acc[nt][mtl][j] * inv[mtl]);
  __syncthreads();

  // out = P @ V : wave owns output rows [w*32, w*32+32)
  f32x4 o[2][4];
#pragma unroll
  for (int i = 0; i < 2; ++i)
#pragma unroll
    for (int dt2 = 0; dt2 < 4; ++dt2)
#pragma unroll
      for (int e = 0; e < 4; ++e) o[i][dt2][e] = 0.f;
#pragma unroll
  for (int ks = 0; ks < 4; ++ks) {
    const int ko = (ks << 12) + lw * 8;
    bf16x8 a0 = *(const bf16x8*)&sP[ko + ((w * 2 + 0) * 16 + ll16) * 32];
    bf16x8 a1 = *(const bf16x8*)&sP[ko + ((w * 2 + 1) * 16 + ll16) * 32];
#pragma unroll
    for (int dt2 = 0; dt2 < 4; ++dt2) {
      bf16x8 bv2 = *(const bf16x8*)&sV[(ks * 4 + lw) * 512 + dt2 * 128 + ll16 * 8];
      o[0][dt2] = __builtin_amdgcn_mfma_f32_16x16x32_bf16(a0, bv2, o[0][dt2], 0, 0, 0);
      o[1][dt2] = __builtin_amdgcn_mfma_f32_16x16x32_bf16(a1, bv2, o[1][dt2], 0, 0, 0);
    }
  }
  __syncthreads();                                    // sP reads done before sOut overwrite

  // stage output tile [128 n][64 d] -> sOut[128][72], then coalesced copy
#pragma unroll
  for (int t2 = 0; t2 < 2; ++t2)
#pragma unroll
    for (int dt2 = 0; dt2 < 4; ++dt2)
#pragma unroll
      for (int j = 0; j < 4; ++j) {
        int rn = w * 32 + t2 * 16 + lw * 4 + j;
        sOut[rn * 72 + dt2 * 16 + ll16] = f2bf(o[t2][dt2][j]);
      }
  __syncthreads();
  const int ob = ((b * 14 + sI) * 128) * 512 + h * 64;
#pragma unroll
  for (int i = 0; i < 4; ++i) {
    int c = t + 256 * i;                              // 0..1023
    int row = c >> 3, ch = c & 7;
    uint4 uu = *(const uint4*)&sOut[row * 72 + ch * 8];
    *(uint4*)&attn_out[ob + row * 512 + ch * 8] = uu;
  }
}

// ------- output projection: out = attn_out @ Wo^T + bo (fp32), XCD-grouped -------
__global__ __launch_bounds__(256) void out_kernel(const u16* __restrict__ attn_out, const u16* __restrict__ wobf,
                                                  const float* __restrict__ bo, float* __restrict__ out) {
  __shared__ u16 sm[32768];                           // 64 KB
  const unsigned u = blockIdx.x;
  const int xcd = u & 7, slot = u >> 3;               // 112 slots/xcd
  const int bx = slot & 3;
  const int by = xcd * 28 + (slot >> 2);              // 0..223
  f32x4 acc[2][8];
#pragma unroll
  for (int i = 0; i < 2; ++i)
#pragma unroll
    for (int j = 0; j < 8; ++j)
#pragma unroll
      for (int e = 0; e < 4; ++e) acc[i][j][e] = 0.f;

  gemm128_db(attn_out + by * 65536, wobf + bx * 65536, sm, acc);

  const int t = threadIdx.x, w = t >> 6, l = t & 63;
  const int lw = l >> 4, ll16 = l & 15;
#pragma unroll
  for (int mt = 0; mt < 8; ++mt) {
    int e = bx * 128 + mt * 16 + ll16;
    float bias = bo[e];
#pragma unroll
    for (int nt = 0; nt < 2; ++nt) {
#pragma unroll
      for (int j = 0; j < 4; ++j) {
        int row = by * 128 + w * 32 + nt * 16 + lw * 4 + j;
        out[row * 512 + e] = acc[nt][mt][j] + bias;
      }
    }
  }
}

extern "C" void kernel_launch(void* const* d_in, const int* in_sizes, int n_in,
                              void* d_out, int out_size, void* d_ws, size_t ws_size,
                              hipStream_t stream) {
  (void)in_sizes; (void)n_in; (void)out_size; (void)ws_size;
  const float* q  = (const float*)d_in[0];
  const float* k  = (const float*)d_in[1];
  const float* v  = (const float*)d_in[2];
  const float* ab = (const float*)d_in[3];
  const float* Wq = (const float*)d_in[4];
  const float* bq = (const float*)d_in[5];
  const float* Wk = (const float*)d_in[6];
  const float* bk = (const float*)d_in[7];
  const float* Wv = (const float*)d_in[8];
  const float* bv = (const float*)d_in[9];
  const float* Wd = (const float*)d_in[10];
  const float* bd = (const float*)d_in[11];
  const float* Wo = (const float*)d_in[12];
  const float* bo = (const float*)d_in[13];
  float* out = (float*)d_out;

  u16* ws = (u16*)d_ws;
  u16* xT      = ws;                    // 3 * 14,680,064
  u16* qh      = ws + 44040192;         // 3 * 14,680,064
  u16* wbf     = ws + 88080384;         // 4 * 262,144
  u16* bias2   = ws;                    // overlays xT (dead after proj): 29,360,128
  u16* attnout = ws + 29360128;         // 14,680,064

  wconv_kernel<<<dim3(1024), dim3(256), 0, stream>>>(Wq, Wk, Wv, Wo, wbf);
  transpose_kernel<<<dim3(28, 8, 48), dim3(256), 0, stream>>>(q, k, v, xT);
  proj_kernel<<<dim3(2688), dim3(256), 0, stream>>>(xT, wbf, bq, bk, bv, qh);
  bias_kernel<<<dim3(128, 16), dim3(256), 0, stream>>>(ab, Wd, bd, bias2);
  attn_kernel<<<dim3(14, 8, 16), dim3(256), 0, stream>>>(qh, qh + 14680064, qh + 29360128, bias2, attnout);
  out_kernel<<<dim3(896), dim3(256), 0, stream>>>(attnout, wbf + 786432, bo, out);
}